// Round 2
// baseline (145.683 us; speedup 1.0000x reference)
//
#include <hip/hip_runtime.h>
#include <hip/hip_bf16.h>

#define NHEADS 8

typedef __bf16 bf16;
typedef __bf16 bf16x4 __attribute__((ext_vector_type(4)));
typedef __bf16 bf16x8 __attribute__((ext_vector_type(8)));
typedef float f32x4 __attribute__((ext_vector_type(4)));

// Layouts (all bf16):
//  Pq/Pk: [bh][lb(32)][c(256)][lp(32)]   elem (bh,c,l) -> ((bh*32 + (l>>5))*256 + c)*32 + (l&31)
//  Vt:    [bh][cb(8)][l(1024)][cp(32)]   elem (bh,l,c) -> ((bh*8 + (c>>5))*1024 + l)*32 + (c&31)
//  Pattn: [bh][db(8)][c(256)][dp(32)]    elem (bh,c,d) -> ((bh*8 + (d>>5))*256 + c)*32 + (d&31)

// ---------------- Kernel A1: q/k grouped conv projection (fused q+k via blockIdx.z)
__global__ __launch_bounds__(256) void proj_qk(
    const float* __restrict__ qin, const float* __restrict__ kin,
    const float* __restrict__ wq, const float* __restrict__ bq,
    const float* __restrict__ wk, const float* __restrict__ bk,
    bf16* __restrict__ Pq, bf16* __restrict__ Pk) {
  int g = blockIdx.x, b = blockIdx.y;
  const float* in   = blockIdx.z ? kin : qin;
  const float* w    = blockIdx.z ? wk : wq;
  const float* bias = blockIdx.z ? bk : bq;
  bf16* out         = blockIdx.z ? Pk : Pq;
  int t = threadIdx.x;
  __shared__ float ch[4096];  // one 64x64 input channel
  {
    const float4* src = reinterpret_cast<const float4*>(in + ((size_t)b*256 + g)*4096);
    float4* dst4 = reinterpret_cast<float4*>(ch);
#pragma unroll
    for (int i = 0; i < 4; i++) dst4[t + i*256] = src[t + i*256];
  }
  float wj[8][4]; float bj[8];
#pragma unroll
  for (int j = 0; j < 8; j++) {
    float4 wv = reinterpret_cast<const float4*>(w)[g*8 + j];
    wj[j][0]=wv.x; wj[j][1]=wv.y; wj[j][2]=wv.z; wj[j][3]=wv.w;
    bj[j] = bias[g*8 + j];
  }
  __syncthreads();
  int h = g >> 5;
  int cbase = (g & 31) * 8;
  int bh = b*8 + h;
#pragma unroll
  for (int li = 0; li < 4; li++) {
    int l = li*256 + t;
    int m = l >> 5, n = l & 31;
    int base = (m*64 + n)*2;
    float c00 = ch[base], c01 = ch[base+1], c10 = ch[base+64], c11 = ch[base+65];
    size_t o0 = (((size_t)bh*32 + m)*256 + cbase)*32 + n;
#pragma unroll
    for (int j = 0; j < 8; j++) {
      float v = bj[j] + wj[j][0]*c00 + wj[j][1]*c01 + wj[j][2]*c10 + wj[j][3]*c11;
      out[o0 + (size_t)j*32] = (bf16)v;
    }
  }
}

// ---------------- Kernel A2: v projection into tiled-transposed Vt
__global__ __launch_bounds__(256) void proj_v(const float* __restrict__ in,
    const float* __restrict__ w, const float* __restrict__ bias,
    bf16* __restrict__ Vt) {
  int m = blockIdx.x, h = blockIdx.y, b = blockIdx.z;
  int t = threadIdx.x;
  __shared__ float ch[32*2*66];  // [g_local][ky][64 + 2 pad]
  {
    int seg = t >> 2, part = t & 3;
    int gl = seg >> 1, ky = seg & 1;
    const float* src = in + (((size_t)b*256 + h*32 + gl)*64 + (2*m + ky))*64;
    float* drow = ch + (gl*2 + ky)*66;
#pragma unroll
    for (int i = 0; i < 4; i++) {
      float4 v = reinterpret_cast<const float4*>(src)[part + i*4];
      int x0 = (part + i*4)*4;
      drow[x0]=v.x; drow[x0+1]=v.y; drow[x0+2]=v.z; drow[x0+3]=v.w;
    }
  }
  __syncthreads();
  int c = t;
  int o = h*256 + c;
  float4 wv = reinterpret_cast<const float4*>(w)[o];
  float bb = bias[o];
  int gl = c >> 3;
  const float* r0 = ch + (gl*2+0)*66;
  const float* r1 = ch + (gl*2+1)*66;
  int bh = b*8 + h;
  bf16* dst = Vt + (((size_t)bh*8 + (c>>5))*1024 + m*32)*32 + (c&31);
#pragma unroll
  for (int n = 0; n < 32; n++) {
    float v = bb + wv.x*r0[2*n] + wv.y*r0[2*n+1] + wv.z*r1[2*n] + wv.w*r1[2*n+1];
    dst[n*32] = (bf16)v;
  }
}

// ---------------- Kernel B: S = Q K^T, softmax -> Pattn.  64 c-rows per block.
// 4 waves, each: 64 c (4 m-frags) x 64 d (4 n-frags).  T14 reg-staged pipeline.
__global__ __launch_bounds__(256) void attn_qk(const bf16* __restrict__ Pq,
    const bf16* __restrict__ Pk, bf16* __restrict__ Pattn) {
  int raw = blockIdx.x;
  int xcd = raw & 7, idx = raw >> 3;
  int bh = xcd*8 + (idx >> 2), tb = idx & 3;   // same-bh blocks share one XCD's L2
  int t = threadIdx.x, wave = t >> 6, lane = t & 63, lg = lane >> 4, lr = lane & 15;
  __shared__ bf16 Kl[256*40];
  __shared__ bf16 Ql[64*40];
  __shared__ float red_s[4][64];
  const float4* Kb4 = reinterpret_cast<const float4*>(Pk + (size_t)bh*32*8192);
  const float4* Qb4 = reinterpret_cast<const float4*>(Pq + (size_t)bh*32*8192);
  float4 kreg[4], qreg;
  int kidx = t*4;
  int qidx = (tb*64 + (t>>2))*4 + (t&3);
#define LOADKQ(kb) { const float4* kp = Kb4 + (size_t)(kb)*1024; \
    kreg[0]=kp[kidx]; kreg[1]=kp[kidx+1]; kreg[2]=kp[kidx+2]; kreg[3]=kp[kidx+3]; \
    qreg = Qb4[(size_t)(kb)*1024 + qidx]; }
  f32x4 acc[4][4];
#pragma unroll
  for (int i = 0; i < 4; i++)
#pragma unroll
    for (int j = 0; j < 4; j++) { f32x4 z = {0.f,0.f,0.f,0.f}; acc[i][j] = z; }
  LOADKQ(0);
  for (int kb = 0; kb < 32; kb++) {
    __syncthreads();              // prior reads of LDS complete
#pragma unroll
    for (int i = 0; i < 4; i++) *reinterpret_cast<float4*>(Kl + t*40 + i*8) = kreg[i];
    *reinterpret_cast<float4*>(Ql + (t>>2)*40 + (t&3)*8) = qreg;
    __syncthreads();              // writes visible
    if (kb < 31) LOADKQ(kb+1);    // global latency hides under MFMA phase
    bf16x8 a[4];
#pragma unroll
    for (int mi = 0; mi < 4; mi++)
      a[mi] = *reinterpret_cast<const bf16x8*>(Ql + (mi*16 + lr)*40 + lg*8);
#pragma unroll
    for (int ni = 0; ni < 4; ni++) {
      bf16x8 bv = *reinterpret_cast<const bf16x8*>(Kl + (wave*64 + ni*16 + lr)*40 + lg*8);
#pragma unroll
      for (int mi = 0; mi < 4; mi++)
        acc[mi][ni] = __builtin_amdgcn_mfma_f32_16x16x32_bf16(a[mi], bv, acc[mi][ni], 0, 0, 0);
    }
  }
#undef LOADKQ
  // softmax over d (wave holds 64 d; combine 4 waves via LDS)
  const float scale = 0.03125f;
#pragma unroll
  for (int mi = 0; mi < 4; mi++)
#pragma unroll
    for (int r = 0; r < 4; r++) {
      float m = fmaxf(fmaxf(acc[mi][0][r], acc[mi][1][r]), fmaxf(acc[mi][2][r], acc[mi][3][r]));
#pragma unroll
      for (int off = 1; off < 16; off <<= 1) m = fmaxf(m, __shfl_xor(m, off, 64));
      red_s[wave][mi*16 + lg*4 + r] = m;
    }
  __syncthreads();
  float sums[4][4];
#pragma unroll
  for (int mi = 0; mi < 4; mi++)
#pragma unroll
    for (int r = 0; r < 4; r++) {
      int c = mi*16 + lg*4 + r;
      float m = fmaxf(fmaxf(red_s[0][c], red_s[1][c]), fmaxf(red_s[2][c], red_s[3][c]));
      float s = 0.f;
#pragma unroll
      for (int ni = 0; ni < 4; ni++) {
        float p = __expf(scale*(acc[mi][ni][r] - m));
        acc[mi][ni][r] = p; s += p;
      }
#pragma unroll
      for (int off = 1; off < 16; off <<= 1) s += __shfl_xor(s, off, 64);
      sums[mi][r] = s;
    }
  __syncthreads();
#pragma unroll
  for (int mi = 0; mi < 4; mi++)
#pragma unroll
    for (int r = 0; r < 4; r++) red_s[wave][mi*16 + lg*4 + r] = sums[mi][r];
  __syncthreads();
#pragma unroll
  for (int mi = 0; mi < 4; mi++)
#pragma unroll
    for (int r = 0; r < 4; r++) {
      int c = mi*16 + lg*4 + r;
      float inv = 1.f / (red_s[0][c] + red_s[1][c] + red_s[2][c] + red_s[3][c]);
      int cg = tb*64 + c;
#pragma unroll
      for (int ni = 0; ni < 4; ni++) {
        int dq = wave*2 + (ni >> 1);
        int dp = (ni & 1)*16 + lr;
        Pattn[((size_t)bh*8 + dq)*8192 + (size_t)cg*32 + dp] = (bf16)(acc[mi][ni][r]*inv);
      }
    }
}

// ---------------- Kernel C: O = Pattn * V, fused deconv + bias + residual
__global__ __launch_bounds__(256) void pv_deconv(const bf16* __restrict__ Pattn,
    const bf16* __restrict__ Vt, const float* __restrict__ qin,
    const float* __restrict__ wo, const float* __restrict__ bo,
    const float* __restrict__ gamma, float* __restrict__ outp) {
  int raw = blockIdx.x;
  int xcd = raw & 7, idx = raw >> 3;             // 1024 blocks: idx 0..127
  int pair = xcd*32 + (idx >> 2);                // (mb,bh) pair, same-V blocks co-XCD
  int tb = idx & 3;
  int mb = pair & 3, bh = pair >> 2;
  int h = bh & 7, b = bh >> 3;
  int t = threadIdx.x, wave = t >> 6, lane = t & 63, lg = lane >> 4, lr = lane & 15;
  __shared__ __attribute__((aligned(16))) char smem[34816];
  bf16* Pl  = reinterpret_cast<bf16*>(smem);           // 64*40*2  = 5120
  bf16* Vl  = reinterpret_cast<bf16*>(smem + 5120);    // 256*40*2 = 20480
  bf16* OlT = reinterpret_cast<bf16*>(smem);           // 256*68*2 = 34816 (after loop)
  __shared__ float wo_s[256];
  __shared__ float bo_s[8];
  wo_s[t] = wo[((size_t)(h*32 + tb*8 + (t>>5)))*32 + (t & 31)];
  if (t < 8) bo_s[t] = bo[h*32 + tb*8 + t];
  const float4* Pb4 = reinterpret_cast<const float4*>(Pattn + (size_t)bh*8*8192 + (size_t)tb*64*32);
  const float4* Vb4 = reinterpret_cast<const float4*>(Vt + ((size_t)bh*8*1024 + mb*256)*32);
  float4 preg, vreg[4];
  int pidx = (t>>2)*4 + (t&3);
  int vidx = t*4;
#define LOADPV(kb) { preg = Pb4[(size_t)(kb)*1024 + pidx]; \
    const float4* vp = Vb4 + (size_t)(kb)*4096; \
    vreg[0]=vp[vidx]; vreg[1]=vp[vidx+1]; vreg[2]=vp[vidx+2]; vreg[3]=vp[vidx+3]; }
  f32x4 acc[4][4];
#pragma unroll
  for (int i = 0; i < 4; i++)
#pragma unroll
    for (int j = 0; j < 4; j++) { f32x4 z = {0.f,0.f,0.f,0.f}; acc[i][j] = z; }
  LOADPV(0);
  for (int kb = 0; kb < 8; kb++) {
    __syncthreads();
    *reinterpret_cast<float4*>(Pl + (t>>2)*40 + (t&3)*8) = preg;
#pragma unroll
    for (int i = 0; i < 4; i++) *reinterpret_cast<float4*>(Vl + t*40 + i*8) = vreg[i];
    __syncthreads();
    if (kb < 7) LOADPV(kb+1);
    bf16x8 a[4];
#pragma unroll
    for (int mi = 0; mi < 4; mi++)
      a[mi] = *reinterpret_cast<const bf16x8*>(Pl + (mi*16 + lr)*40 + lg*8);
#pragma unroll
    for (int ni = 0; ni < 4; ni++) {
      bf16x8 bv = *reinterpret_cast<const bf16x8*>(Vl + (wave*64 + ni*16 + lr)*40 + lg*8);
#pragma unroll
      for (int mi = 0; mi < 4; mi++)
        acc[mi][ni] = __builtin_amdgcn_mfma_f32_16x16x32_bf16(a[mi], bv, acc[mi][ni], 0, 0, 0);
    }
  }
#undef LOADPV
  __syncthreads();   // all MFMA LDS reads done before OlT overwrites
#pragma unroll
  for (int mi = 0; mi < 4; mi++)
#pragma unroll
    for (int ni = 0; ni < 4; ni++) {
      int l = wave*64 + ni*16 + lr;
      int cb = mi*16 + lg*4;
      bf16x4 p;
      p[0] = (bf16)acc[mi][ni][0]; p[1] = (bf16)acc[mi][ni][1];
      p[2] = (bf16)acc[mi][ni][2]; p[3] = (bf16)acc[mi][ni][3];
      *reinterpret_cast<bf16x4*>(OlT + l*68 + cb) = p;
    }
  __syncthreads();
  // epilogue: per thread fixed (ct, xq, r); loops over it -> ml
  int xq = t & 15, b5 = (t >> 4) & 1, ct = t >> 5;
  int r = b5;
  float2 wp[8];
#pragma unroll
  for (int j = 0; j < 8; j++)
    wp[j] = *reinterpret_cast<const float2*>(wo_s + ct*32 + j*4 + (1 - r)*2);
  float bias = bo_s[ct];
  float gm = gamma[0];
  int co = h*32 + tb*8 + ct;
#pragma unroll
  for (int it = 0; it < 8; it++) {
    int y = it*2 + b5;
    int ll0 = it*32 + xq*2;
    bf16x4 o00 = *reinterpret_cast<const bf16x4*>(OlT + ll0*68 + ct*8);
    bf16x4 o01 = *reinterpret_cast<const bf16x4*>(OlT + ll0*68 + ct*8 + 4);
    bf16x4 o10 = *reinterpret_cast<const bf16x4*>(OlT + (ll0+1)*68 + ct*8);
    bf16x4 o11 = *reinterpret_cast<const bf16x4*>(OlT + (ll0+1)*68 + ct*8 + 4);
    float v0 = bias, v1 = bias, v2 = bias, v3 = bias;
#pragma unroll
    for (int j = 0; j < 4; j++) {
      float f0 = (float)o00[j], f1 = (float)o01[j];
      v0 += f0*wp[j].y;   v1 += f0*wp[j].x;
      v0 += f1*wp[4+j].y; v1 += f1*wp[4+j].x;
      float g0 = (float)o10[j], g1 = (float)o11[j];
      v2 += g0*wp[j].y;   v3 += g0*wp[j].x;
      v2 += g1*wp[4+j].y; v3 += g1*wp[4+j].x;
    }
    size_t oi = (((size_t)b*256 + co)*64 + (mb*16 + y))*64 + xq*4;
    float4 qv = *reinterpret_cast<const float4*>(qin + oi);
    float4 ov;
    ov.x = qv.x + gm*v0; ov.y = qv.y + gm*v1;
    ov.z = qv.z + gm*v2; ov.w = qv.w + gm*v3;
    *reinterpret_cast<float4*>(outp + oi) = ov;
  }
}

extern "C" void kernel_launch(void* const* d_in, const int* in_sizes, int n_in,
                              void* d_out, int out_size, void* d_ws, size_t ws_size,
                              hipStream_t stream) {
  const float* q  = (const float*)d_in[0];
  const float* k  = (const float*)d_in[1];
  const float* v  = (const float*)d_in[2];
  const float* wq = (const float*)d_in[3];
  const float* bq = (const float*)d_in[4];
  const float* wk = (const float*)d_in[5];
  const float* bk = (const float*)d_in[6];
  const float* wv = (const float*)d_in[7];
  const float* bv = (const float*)d_in[8];
  const float* wo = (const float*)d_in[9];
  const float* bo = (const float*)d_in[10];
  const float* gamma = (const float*)d_in[11];
  float* out = (float*)d_out;

  char* ws = (char*)d_ws;
  bf16* Pq    = (bf16*)(ws);              //  33,554,432 B
  bf16* Pk    = (bf16*)(ws + 33554432);   //  33,554,432 B
  bf16* Vt    = (bf16*)(ws + 67108864);   //  33,554,432 B
  bf16* Pattn = (bf16*)(ws + 100663296);  //   8,388,608 B

  proj_qk<<<dim3(256, 8, 2), 256, 0, stream>>>(q, k, wq, bq, wk, bk, Pq, Pk);
  proj_v <<<dim3(32, 8, 8), 256, 0, stream>>>(v, wv, bv, Vt);
  attn_qk<<<dim3(256), 256, 0, stream>>>(Pq, Pk, Pattn);
  pv_deconv<<<dim3(1024), 256, 0, stream>>>(Pattn, Vt, q, wo, bo, gamma, out);
}

// Round 3
// 91.711 us; speedup vs baseline: 1.5885x; 1.5885x over previous
//
#include <hip/hip_runtime.h>
#include <hip/hip_bf16.h>

typedef __bf16 bf16;
typedef __bf16 bf16x4 __attribute__((ext_vector_type(4)));
typedef __bf16 bf16x8 __attribute__((ext_vector_type(8)));
typedef float f32x4 __attribute__((ext_vector_type(4)));

// async global->LDS, 16B per lane. LDS dest must be wave-uniform (base+lane*16 is HW).
__device__ __forceinline__ void gload16(const void* g, void* l) {
  __builtin_amdgcn_global_load_lds(
      (const __attribute__((address_space(1))) unsigned int*)g,
      (__attribute__((address_space(3))) unsigned int*)l, 16, 0, 0);
}

// Layouts (bf16, BK=64 chunks, 128B rows, swizzle: elem col ^= (row&7)<<3):
//  Pq/Pk: [bh][kb16][row c(256)][64]   (k-dim = l)  row-XOR uses c&7
//  Vt:    [bh][kb4][row l(1024)][64]   (k-dim = c)  row-XOR uses l&7
//  Pattn: [bh][kb4][row c(256)][64]    (k-dim = d)  row-XOR uses c&7

// ---------------- Kernel A1: q/k grouped conv projection (fused q+k via blockIdx.z)
__global__ __launch_bounds__(256) void proj_qk(
    const float* __restrict__ qin, const float* __restrict__ kin,
    const float* __restrict__ wq, const float* __restrict__ bq,
    const float* __restrict__ wk, const float* __restrict__ bk,
    bf16* __restrict__ Pq, bf16* __restrict__ Pk) {
  int g = blockIdx.x, b = blockIdx.y;
  const float* in   = blockIdx.z ? kin : qin;
  const float* w    = blockIdx.z ? wk : wq;
  const float* bias = blockIdx.z ? bk : bq;
  bf16* out         = blockIdx.z ? Pk : Pq;
  int t = threadIdx.x;
  __shared__ float ch[4096];  // one 64x64 input channel
  {
    const float4* src = reinterpret_cast<const float4*>(in + ((size_t)b*256 + g)*4096);
    float4* dst4 = reinterpret_cast<float4*>(ch);
#pragma unroll
    for (int i = 0; i < 4; i++) dst4[t + i*256] = src[t + i*256];
  }
  int j = t >> 5, i = t & 31;
  float4 wv = reinterpret_cast<const float4*>(w)[g*8 + j];
  float bj = bias[g*8 + j];
  __syncthreads();
  int h = g >> 5;
  int c = (g & 31)*8 + j;
  int bh = b*8 + h;
#pragma unroll
  for (int p = 0; p < 4; p++) {
    int l0 = p*256 + i*8;
    int m = l0 >> 5, kb = l0 >> 6, kp0 = l0 & 63, n0 = l0 & 31;
    float rr0[16], rr1[16];
    const float4* R0 = reinterpret_cast<const float4*>(ch + (2*m)*64 + 2*n0);
    const float4* R1 = reinterpret_cast<const float4*>(ch + (2*m+1)*64 + 2*n0);
#pragma unroll
    for (int u = 0; u < 4; u++) {
      *reinterpret_cast<float4*>(rr0 + u*4) = R0[u];
      *reinterpret_cast<float4*>(rr1 + u*4) = R1[u];
    }
    bf16x8 o;
#pragma unroll
    for (int u = 0; u < 8; u++)
      o[u] = (bf16)(bj + wv.x*rr0[2*u] + wv.y*rr0[2*u+1] + wv.z*rr1[2*u] + wv.w*rr1[2*u+1]);
    size_t off = (((size_t)bh*16 + kb)*256 + c)*64 + (kp0 ^ (j << 3));
    *reinterpret_cast<bf16x8*>(out + off) = o;
  }
}

// ---------------- Kernel A2: v projection into swizzled chunk-transposed Vt
__global__ __launch_bounds__(256) void proj_v(const float* __restrict__ in,
    const float* __restrict__ w, const float* __restrict__ bias,
    bf16* __restrict__ Vt) {
  int m = blockIdx.x, h = blockIdx.y, b = blockIdx.z;
  int t = threadIdx.x;
  __shared__ float ch[32*2*66];  // [g_local][ky][64 + 2 pad]
  {
    int seg = t >> 2, part = t & 3;
    int gl = seg >> 1, ky = seg & 1;
    const float* src = in + (((size_t)b*256 + h*32 + gl)*64 + (2*m + ky))*64;
    float* drow = ch + (gl*2 + ky)*66;
#pragma unroll
    for (int i = 0; i < 4; i++) {
      float4 v = reinterpret_cast<const float4*>(src)[part + i*4];
      int x0 = (part + i*4)*4;
      drow[x0]=v.x; drow[x0+1]=v.y; drow[x0+2]=v.z; drow[x0+3]=v.w;
    }
  }
  int cgrp = t & 31, lgr = t >> 5;
  int c0 = cgrp*8;
  float4 wv8[8]; float bb8[8];
#pragma unroll
  for (int u = 0; u < 8; u++) {
    wv8[u] = reinterpret_cast<const float4*>(w)[h*256 + c0 + u];
    bb8[u] = bias[h*256 + c0 + u];
  }
  __syncthreads();
  const float* r0 = ch + (cgrp*2 + 0)*66;
  const float* r1 = ch + (cgrp*2 + 1)*66;
  int bh = b*8 + h;
  bf16* base = Vt + ((size_t)bh*4 + (c0 >> 6))*1024*64;
  int colx = (c0 & 63) ^ (lgr << 3);    // (l&7)==lgr by construction
#pragma unroll
  for (int p = 0; p < 4; p++) {
    int n = p*8 + lgr;
    int l = m*32 + n;
    float c00 = r0[2*n], c01 = r0[2*n+1], c10 = r1[2*n], c11 = r1[2*n+1];
    bf16x8 o;
#pragma unroll
    for (int u = 0; u < 8; u++)
      o[u] = (bf16)(bb8[u] + wv8[u].x*c00 + wv8[u].y*c01 + wv8[u].z*c10 + wv8[u].w*c11);
    *reinterpret_cast<bf16x8*>(base + (size_t)l*64 + colx) = o;
  }
}

// ---------------- Kernel B: S = Q K^T (K=1024), softmax -> Pattn. 32 c-rows/block.
// 512 blocks, 4 waves; wave tile 32c x 64d (2x4 frags). global_load_lds staging.
__global__ __launch_bounds__(256, 2) void attn_qk(const bf16* __restrict__ Pq,
    const bf16* __restrict__ Pk, bf16* __restrict__ Pattn) {
  int raw = blockIdx.x;
  int loc = raw >> 3;
  int bh = (raw & 7)*8 + (loc >> 3);   // 8 c-strips of one bh share an XCD
  int tb = loc & 7;
  int c0 = tb*32;
  int t = threadIdx.x, wave = t >> 6, lane = t & 63, lg = lane >> 4, lr = lane & 15;
  __shared__ bf16 Kl[256*64];     // 32 KB, one K chunk (linear, pre-swizzled in global)
  __shared__ bf16 Ql[32*64];      // 4 KB
  __shared__ float red_s[4][32];
  const char* Kbase = (const char*)Pk + (size_t)bh*16*32768;
  const char* Qbase = (const char*)Pq + ((size_t)bh*16*256 + c0)*128;
  f32x4 acc[2][4];
#pragma unroll
  for (int i = 0; i < 2; i++)
#pragma unroll
    for (int j = 0; j < 4; j++) { f32x4 z = {0.f,0.f,0.f,0.f}; acc[i][j] = z; }
  for (int kb = 0; kb < 16; kb++) {
    __syncthreads();                       // prior chunk's LDS reads done
    {
      const char* kc = Kbase + (size_t)kb*32768 + wave*8192 + lane*16;
      char* kl = (char*)Kl + wave*8192;
#pragma unroll
      for (int i = 0; i < 8; i++) gload16(kc + i*1024, kl + i*1024);
      gload16(Qbase + (size_t)kb*32768 + wave*1024 + lane*16, (char*)Ql + wave*1024);
    }
    __syncthreads();                       // barrier drains vmcnt -> LDS filled
#pragma unroll
    for (int ks = 0; ks < 2; ks++) {
      int colx = (ks*32 + lg*8) ^ ((lr & 7) << 3);
      bf16x8 a0 = *reinterpret_cast<const bf16x8*>(Ql + lr*64 + colx);
      bf16x8 a1 = *reinterpret_cast<const bf16x8*>(Ql + (16 + lr)*64 + colx);
#pragma unroll
      for (int ni = 0; ni < 4; ni++) {
        bf16x8 bv = *reinterpret_cast<const bf16x8*>(Kl + (wave*64 + ni*16 + lr)*64 + colx);
        acc[0][ni] = __builtin_amdgcn_mfma_f32_16x16x32_bf16(a0, bv, acc[0][ni], 0, 0, 0);
        acc[1][ni] = __builtin_amdgcn_mfma_f32_16x16x32_bf16(a1, bv, acc[1][ni], 0, 0, 0);
      }
    }
  }
  // softmax over d (wave holds 64 d; combine 4 waves via red_s)
  const float scale = 0.03125f;
  float sums[2][4];
#pragma unroll
  for (int mi = 0; mi < 2; mi++)
#pragma unroll
    for (int r = 0; r < 4; r++) {
      float mx = fmaxf(fmaxf(acc[mi][0][r], acc[mi][1][r]), fmaxf(acc[mi][2][r], acc[mi][3][r]));
#pragma unroll
      for (int off = 1; off < 16; off <<= 1) mx = fmaxf(mx, __shfl_xor(mx, off, 64));
      red_s[wave][mi*16 + lg*4 + r] = mx;
    }
  __syncthreads();
#pragma unroll
  for (int mi = 0; mi < 2; mi++)
#pragma unroll
    for (int r = 0; r < 4; r++) {
      int cl = mi*16 + lg*4 + r;
      float mx = fmaxf(fmaxf(red_s[0][cl], red_s[1][cl]), fmaxf(red_s[2][cl], red_s[3][cl]));
      float s = 0.f;
#pragma unroll
      for (int ni = 0; ni < 4; ni++) {
        float p = __expf(scale*(acc[mi][ni][r] - mx));
        acc[mi][ni][r] = p; s += p;
      }
#pragma unroll
      for (int off = 1; off < 16; off <<= 1) s += __shfl_xor(s, off, 64);
      sums[mi][r] = s;
    }
  __syncthreads();
#pragma unroll
  for (int mi = 0; mi < 2; mi++)
#pragma unroll
    for (int r = 0; r < 4; r++) red_s[wave][mi*16 + lg*4 + r] = sums[mi][r];
  __syncthreads();
  // normalize + stage P strip into LDS (reuse Kl) in swizzled chunk layout
  bf16* Pst = Kl;
#pragma unroll
  for (int mi = 0; mi < 2; mi++)
#pragma unroll
    for (int r = 0; r < 4; r++) {
      int cl = mi*16 + lg*4 + r;
      float iv = 1.f/(red_s[0][cl] + red_s[1][cl] + red_s[2][cl] + red_s[3][cl]);
#pragma unroll
      for (int ni = 0; ni < 4; ni++) {
        int dl = ni*16 + lr;
        Pst[wave*2048 + cl*64 + (dl ^ ((cl & 7) << 3))] = (bf16)(acc[mi][ni][r]*iv);
      }
    }
  __syncthreads();
  // coalesced copy-out: 4 pieces of 4KB
  const uint4* ls = reinterpret_cast<const uint4*>(Kl);
#pragma unroll
  for (int i = 0; i < 4; i++) {
    uint4* gp = reinterpret_cast<uint4*>((char*)Pattn + (((size_t)bh*4 + i)*256 + c0)*128);
    gp[t] = ls[i*256 + t];
  }
}

// ---------------- Kernel C: O = Pattn * V (K=256), fused deconv + bias + residual
__global__ __launch_bounds__(256, 4) void pv_deconv(const bf16* __restrict__ Pattn,
    const bf16* __restrict__ Vt, const float* __restrict__ qin,
    const float* __restrict__ wo, const float* __restrict__ bo,
    const float* __restrict__ gamma, float* __restrict__ outp) {
  int raw = blockIdx.x;
  int idx = raw >> 3;
  int pair = (raw & 7)*32 + (idx >> 2);   // (mb,bh); 4 tb-blocks share V chunk + XCD
  int tb = idx & 3;
  int mb = pair & 3, bh = pair >> 2;
  int h = bh & 7, b = bh >> 3;
  int t = threadIdx.x, wave = t >> 6, lane = t & 63, lg = lane >> 4, lr = lane & 15;
  __shared__ __attribute__((aligned(16))) char smem[40960];
  bf16* Pl   = reinterpret_cast<bf16*>(smem);            // 8192 B
  bf16* Vl   = reinterpret_cast<bf16*>(smem + 8192);     // 32768 B
  bf16* OlT  = reinterpret_cast<bf16*>(smem);            // 256*66*2 = 33792 B (post-loop)
  float* wo_s = reinterpret_cast<float*>(smem + 36864);  // 1024 B (post-loop)
  float* bo_s = reinterpret_cast<float*>(smem + 37888);  // 32 B
  const char* Pbase = (const char*)Pattn + ((size_t)bh*4*256 + tb*64)*128;
  const char* Vbase = (const char*)Vt + ((size_t)bh*4*1024 + mb*256)*128;
  f32x4 acc[4][4];
#pragma unroll
  for (int i = 0; i < 4; i++)
#pragma unroll
    for (int j = 0; j < 4; j++) { f32x4 z = {0.f,0.f,0.f,0.f}; acc[i][j] = z; }
  for (int kb = 0; kb < 4; kb++) {
    __syncthreads();
    {
      const char* pc = Pbase + (size_t)kb*32768 + wave*2048 + lane*16;
      char* pl = (char*)Pl + wave*2048;
#pragma unroll
      for (int i = 0; i < 2; i++) gload16(pc + i*1024, pl + i*1024);
      const char* vc = Vbase + (size_t)kb*131072 + wave*8192 + lane*16;
      char* vl = (char*)Vl + wave*8192;
#pragma unroll
      for (int i = 0; i < 8; i++) gload16(vc + i*1024, vl + i*1024);
    }
    __syncthreads();
#pragma unroll
    for (int ks = 0; ks < 2; ks++) {
      int colx = (ks*32 + lg*8) ^ ((lr & 7) << 3);
      bf16x8 a[4];
#pragma unroll
      for (int mi = 0; mi < 4; mi++)
        a[mi] = *reinterpret_cast<const bf16x8*>(Pl + (mi*16 + lr)*64 + colx);
#pragma unroll
      for (int ni = 0; ni < 4; ni++) {
        bf16x8 bv = *reinterpret_cast<const bf16x8*>(Vl + (wave*64 + ni*16 + lr)*64 + colx);
#pragma unroll
        for (int mi = 0; mi < 4; mi++)
          acc[mi][ni] = __builtin_amdgcn_mfma_f32_16x16x32_bf16(a[mi], bv, acc[mi][ni], 0, 0, 0);
      }
    }
  }
  __syncthreads();   // all MFMA LDS reads done before OlT/wo_s overwrite
#pragma unroll
  for (int mi = 0; mi < 4; mi++)
#pragma unroll
    for (int ni = 0; ni < 4; ni++) {
      int l = wave*64 + ni*16 + lr;
      int cb = mi*16 + lg*4;
      bf16x4 p;
      p[0] = (bf16)acc[mi][ni][0]; p[1] = (bf16)acc[mi][ni][1];
      p[2] = (bf16)acc[mi][ni][2]; p[3] = (bf16)acc[mi][ni][3];
      *reinterpret_cast<bf16x4*>(OlT + l*66 + cb) = p;
    }
  wo_s[t] = wo[((size_t)(h*32 + tb*8 + (t>>5)))*32 + (t & 31)];
  if (t < 8) bo_s[t] = bo[h*32 + tb*8 + t];
  __syncthreads();
  // epilogue: deconv 2x2 stride 2 + bias + residual; fully coalesced float4 I/O
  int xq = t & 15, b5 = (t >> 4) & 1, ct = t >> 5;
  float2 wp[8];
#pragma unroll
  for (int j = 0; j < 8; j++)
    wp[j] = *reinterpret_cast<const float2*>(wo_s + ct*32 + j*4 + (1 - b5)*2);
  float bias = bo_s[ct];
  float gm = gamma[0];
  int co = h*32 + tb*8 + ct;
#pragma unroll
  for (int it = 0; it < 8; it++) {
    int y = it*2 + b5;
    int ll0 = it*32 + xq*2;
    bf16x4 o00 = *reinterpret_cast<const bf16x4*>(OlT + ll0*66 + ct*8);
    bf16x4 o01 = *reinterpret_cast<const bf16x4*>(OlT + ll0*66 + ct*8 + 4);
    bf16x4 o10 = *reinterpret_cast<const bf16x4*>(OlT + (ll0+1)*66 + ct*8);
    bf16x4 o11 = *reinterpret_cast<const bf16x4*>(OlT + (ll0+1)*66 + ct*8 + 4);
    float v0 = bias, v1 = bias, v2 = bias, v3 = bias;
#pragma unroll
    for (int j = 0; j < 4; j++) {
      float f0 = (float)o00[j], f1 = (float)o01[j];
      v0 += f0*wp[j].y;   v1 += f0*wp[j].x;
      v0 += f1*wp[4+j].y; v1 += f1*wp[4+j].x;
      float g0 = (float)o10[j], g1 = (float)o11[j];
      v2 += g0*wp[j].y;   v3 += g0*wp[j].x;
      v2 += g1*wp[4+j].y; v3 += g1*wp[4+j].x;
    }
    size_t oi = (((size_t)b*256 + co)*64 + (mb*16 + y))*64 + xq*4;
    float4 qv = *reinterpret_cast<const float4*>(qin + oi);
    float4 ov;
    ov.x = qv.x + gm*v0; ov.y = qv.y + gm*v1;
    ov.z = qv.z + gm*v2; ov.w = qv.w + gm*v3;
    *reinterpret_cast<float4*>(outp + oi) = ov;
  }
}

extern "C" void kernel_launch(void* const* d_in, const int* in_sizes, int n_in,
                              void* d_out, int out_size, void* d_ws, size_t ws_size,
                              hipStream_t stream) {
  const float* q  = (const float*)d_in[0];
  const float* k  = (const float*)d_in[1];
  const float* v  = (const float*)d_in[2];
  const float* wq = (const float*)d_in[3];
  const float* bq = (const float*)d_in[4];
  const float* wk = (const float*)d_in[5];
  const float* bk = (const float*)d_in[6];
  const float* wv = (const float*)d_in[7];
  const float* bv = (const float*)d_in[8];
  const float* wo = (const float*)d_in[9];
  const float* bo = (const float*)d_in[10];
  const float* gamma = (const float*)d_in[11];
  float* out = (float*)d_out;

  char* ws = (char*)d_ws;
  bf16* Pq    = (bf16*)(ws);              //  33,554,432 B
  bf16* Pk    = (bf16*)(ws + 33554432);   //  33,554,432 B
  bf16* Vt    = (bf16*)(ws + 67108864);   //  33,554,432 B
  bf16* Pattn = (bf16*)(ws + 100663296);  //   8,388,608 B

  proj_qk<<<dim3(256, 8, 2), 256, 0, stream>>>(q, k, wq, bq, wk, bk, Pq, Pk);
  proj_v <<<dim3(32, 8, 8), 256, 0, stream>>>(v, wv, bv, Vt);
  attn_qk<<<dim3(512), 256, 0, stream>>>(Pq, Pk, Pattn);
  pv_deconv<<<dim3(1024), 256, 0, stream>>>(Pattn, Vt, q, wo, bo, gamma, out);
}